// Round 1
// baseline (155.024 us; speedup 1.0000x reference)
//
#include <hip/hip_runtime.h>
#include <stdint.h>
#include <math.h>

// MulHeadAttn on MI355X. B=2, C=1024, E=1024, head_dim(H)=16, n_heads(HD)=64.
// cast(fp32->bf16, Wq pre-scaled 0.25*log2e) -> fused QKV bf16-MFMA GEMM
// (R9: global_load_lds width-16 + double-buffered LDS, m97 structure) ->
// MFMA flash attention (no-max softmax in exp2 domain; transposed QK;
// v_perm P-pack) -> bf16-MFMA O-projection.

typedef __bf16   bf16x8 __attribute__((ext_vector_type(8)));
typedef float    f32x4  __attribute__((ext_vector_type(4)));

__device__ __forceinline__ unsigned short f2bf(float f) {
    unsigned int u = __float_as_uint(f);
    u += 0x7FFFu + ((u >> 16) & 1u);         // round-to-nearest-even
    return (unsigned short)(u >> 16);
}
__device__ __forceinline__ float bflo(unsigned int u) { return __uint_as_float(u << 16); }
__device__ __forceinline__ float bfhi(unsigned int u) { return __uint_as_float(u & 0xFFFF0000u); }

// pack two fp32 -> two bf16 (round-nearest-ties-away): 2 adds + 1 v_perm
__device__ __forceinline__ unsigned int pkbf(float lo, float hi) {
    const unsigned int ulo = __float_as_uint(lo) + 0x8000u;
    const unsigned int uhi = __float_as_uint(hi) + 0x8000u;
    return __builtin_amdgcn_perm(uhi, ulo, 0x07060302u);  // [uhi.hi16 | ulo.hi16]
}

// async global->LDS, 16 bytes per lane (dest = wave-uniform base + lane*16)
__device__ __forceinline__ void gl16(const unsigned short* g, unsigned short* l) {
    __builtin_amdgcn_global_load_lds(
        (const __attribute__((address_space(1))) unsigned int*)g,
        (__attribute__((address_space(3))) unsigned int*)l, 16, 0, 0);
}

// ---------------------------------------------------------------- cast ----
// z=0,1: halves of x; z=2: Wq scaled 0.25*log2(e) (softmax scale folded into
// the exp2 domain); z=3..5: Wk, Wv, Wo.
__global__ __launch_bounds__(256) void cast_to_bf16(
    const float* __restrict__ x,
    const float* __restrict__ w0, const float* __restrict__ w1,
    const float* __restrict__ w2, const float* __restrict__ w3,
    unsigned short* __restrict__ xb,
    unsigned short* __restrict__ b0, unsigned short* __restrict__ b1,
    unsigned short* __restrict__ b2, unsigned short* __restrict__ b3)
{
    const int z = blockIdx.y;
    const float* src;
    unsigned short* dst;
    size_t off = 0;
    float sc = 1.f;
    if (z < 2)       { src = x;  dst = xb; off = (size_t)z << 20; }
    else if (z == 2) { src = w0; dst = b0; sc = 0.36067376022224085f; } // 0.25*log2e
    else if (z == 3) { src = w1; dst = b1; }
    else if (z == 4) { src = w2; dst = b2; }
    else             { src = w3; dst = b3; }
    const size_t i = off + ((size_t)blockIdx.x * 256 + threadIdx.x) * 4;
    const float4 v = *(const float4*)(src + i);
    *(ushort4*)(dst + i) = make_ushort4(f2bf(v.x * sc), f2bf(v.y * sc),
                                        f2bf(v.z * sc), f2bf(v.w * sc));
}

// ---------------------------------------------------------------- GEMM ----
// R9: 64x128 tile, double-buffered LDS, global_load_lds width-16 staging
// (m97 structure: one barrier per K-step; stage for tile k+1 issued right
// after the barrier, drained by the next barrier's implicit vmcnt(0)).
// Per-thread source addresses are lane-linear and match the gload_lds dest
// layout: LDS byte offset 16*t  <=>  row t>>2, col (t&3)*8 of [rows][32].
__global__ __launch_bounds__(256) void gemm_bt_mfma(
    const unsigned short* __restrict__ A,
    const unsigned short* __restrict__ B0, const unsigned short* __restrict__ B1,
    const unsigned short* __restrict__ B2,
    void* __restrict__ C0, void* __restrict__ C1, void* __restrict__ C2,
    int M, int N, int K, int bf16out)
{
    const unsigned short* Bm = (blockIdx.z == 0) ? B0 : (blockIdx.z == 1) ? B1 : B2;
    void* Cm                 = (blockIdx.z == 0) ? C0 : (blockIdx.z == 1) ? C1 : C2;

    __shared__ __align__(16) unsigned short As[2][64 * 32];   //  8 KB
    __shared__ __align__(16) unsigned short Bs[2][128 * 32];  // 16 KB

    const int t    = threadIdx.x;
    const int lane = t & 63;
    const int w    = t >> 6;
    const int m0   = blockIdx.y * 64;
    const int n0   = blockIdx.x * 128;
    const int wm   = (w & 1) * 32;
    const int wn   = (w >> 1) * 64;

    // staging addresses: thread t covers row t>>2, cols (t&3)*8 .. +8
    const int r0 = t >> 2;
    const int c0 = (t & 3) * 8;
    const unsigned short* Apa = A  + (size_t)(m0 + r0) * K + c0;
    const unsigned short* Bpa = Bm + (size_t)(n0 + r0) * K + c0;
    const unsigned short* Bpb = Bm + (size_t)(n0 + r0 + 64) * K + c0;
    // wave-uniform LDS bases: wave w stages 1 KB = 16 rows of [.][32]
    unsigned short* ldsA  = &As[0][w * 512];
    unsigned short* ldsB0 = &Bs[0][w * 512];
    unsigned short* ldsB1 = &Bs[0][2048 + w * 512];
    const int bufStrA = 64 * 32;    // u16 elements per A buffer
    const int bufStrB = 128 * 32;

    f32x4 acc[2][4];
#pragma unroll
    for (int i = 0; i < 2; ++i)
#pragma unroll
        for (int j = 0; j < 4; ++j) acc[i][j] = (f32x4){0.f, 0.f, 0.f, 0.f};

    const int fm = lane & 15;
    const int kg = lane >> 4;

    // prologue: stage tile 0 into buffer 0
    gl16(Apa, ldsA);
    gl16(Bpa, ldsB0);
    gl16(Bpb, ldsB1);

    int cur = 0;
    for (int k0 = 0; k0 < K; k0 += 32) {
        // drains vmcnt(0)+lgkmcnt(0): buf[cur] staged, all prior reads done
        __syncthreads();

        if (k0 + 32 < K) {   // stage next tile into buf[cur^1]
            const int nb = (cur ^ 1);
            gl16(Apa + k0 + 32, ldsA  + nb * bufStrA);
            gl16(Bpa + k0 + 32, ldsB0 + nb * bufStrB);
            gl16(Bpb + k0 + 32, ldsB1 + nb * bufStrB);
        }

        const unsigned short* Ab = &As[cur][0];
        const unsigned short* Bb = &Bs[cur][0];
        bf16x8 af[2], bfr[4];
#pragma unroll
        for (int im = 0; im < 2; ++im)
            af[im] = *(const bf16x8*)&Ab[(wm + im * 16 + fm) * 32 + kg * 8];
#pragma unroll
        for (int in = 0; in < 4; ++in)
            bfr[in] = *(const bf16x8*)&Bb[(wn + in * 16 + fm) * 32 + kg * 8];
#pragma unroll
        for (int im = 0; im < 2; ++im)
#pragma unroll
            for (int in = 0; in < 4; ++in)
                acc[im][in] = __builtin_amdgcn_mfma_f32_16x16x32_bf16(
                    af[im], bfr[in], acc[im][in], 0, 0, 0);

        cur ^= 1;
    }

#pragma unroll
    for (int im = 0; im < 2; ++im) {
#pragma unroll
        for (int in = 0; in < 4; ++in) {
            const int row = m0 + wm + im * 16 + kg * 4;
            const int col = n0 + wn + in * 16 + fm;
            if (bf16out) {
                unsigned short* cp = (unsigned short*)Cm;
#pragma unroll
                for (int r = 0; r < 4; ++r)
                    cp[(size_t)(row + r) * N + col] = f2bf(acc[im][in][r]);
            } else {
                float* cp = (float*)Cm;
#pragma unroll
                for (int r = 0; r < 4; ++r)
                    cp[(size_t)(row + r) * N + col] = acc[im][in][r];
            }
        }
    }
}

// ----------------------------------------------------------- attention ----
// grid (8, 128): one block = one (b,hd) x 128 q-rows -> 1024 blocks = 4/CU.
// 4 waves; wave wq owns q-rows [wq*32, wq*32+32). Per 64-key tile:
//   - stage K [64][KSTR2] bf16 (d=16 real + 16 zero-pad) and V transposed
//   - QK transposed: s = mfma(K_frag, Q_frag); lane = (key quad, q=fm)
//   - p = exp2(s)  (scale*log2e folded into Wq; softmax base-invariant)
//   - pack pairs via +0x8000 + v_perm (RNTA) -> ds_write_b64 into Ps[q][key]
//   - PV: P rows as A-frags (wave-local), V^T as B-frags
#define KSTR2 40
#define VSTR2 72
#define PSTR  80

__global__ __launch_bounds__(256) void attn_mfma(
    const unsigned short* __restrict__ Qb, const unsigned short* __restrict__ Kb,
    const unsigned short* __restrict__ Vb, unsigned short* __restrict__ Ob)
{
    __shared__ __align__(16) unsigned short Ks[64 * KSTR2];    //  5.0 KB
    __shared__ __align__(16) unsigned short VsT[16 * VSTR2];   //  2.3 KB
    __shared__ __align__(16) unsigned short Ps[128 * PSTR];    // 20.0 KB
    __shared__ __align__(16) float Lsh[128];                   //  0.5 KB

    const int t    = threadIdx.x;
    const int lane = t & 63;
    const int wq   = t >> 6;
    const int fm   = lane & 15;
    const int kg   = lane >> 4;
    const int bh   = blockIdx.y;
    const size_t base = ((size_t)(bh >> 6) * 1024) * 1024 + (size_t)(bh & 63) * 16;
    const int q0 = blockIdx.x * 128;

    // zero the K k-pad once (real cols rewritten per tile, pad never)
    if (t < 128) {
        const int row = t >> 1, seg = t & 1;
        *(uint4*)&Ks[row * KSTR2 + 16 + seg * 8] = make_uint4(0, 0, 0, 0);
    }

    // Q fragments (B-operand): row q0+wq*32+m*16+fm, k=kg*8 (zero kg>=2)
    union { uint4 u; bf16x8 h; } zz; zz.u = make_uint4(0, 0, 0, 0);
    bf16x8 aq[2];
#pragma unroll
    for (int m = 0; m < 2; ++m) {
        if (kg < 2)
            aq[m] = *(const bf16x8*)(Qb + base +
                     (size_t)(q0 + wq * 32 + m * 16 + fm) * 1024 + kg * 8);
        else
            aq[m] = zz.h;
    }

    f32x4 oacc[2];
    float lp[2];
#pragma unroll
    for (int m = 0; m < 2; ++m) {
        oacc[m] = (f32x4){0.f, 0.f, 0.f, 0.f};
        lp[m] = 0.f;
    }

    for (int kt = 0; kt < 1024; kt += 64) {
        __syncthreads();
        if (t < 128) {           // K tile: 64 rows x 16 real bf16
            const int row = t >> 1, seg = t & 1;
            *(uint4*)&Ks[row * KSTR2 + seg * 8] =
                *(const uint4*)(Kb + base + (size_t)(kt + row) * 1024 + seg * 8);
        } else {                 // V tile, transposed: VsT[d][key]
            const int idx = t - 128;
            const int key = idx >> 1, half = idx & 1;
            uint4 v = *(const uint4*)(Vb + base + (size_t)(kt + key) * 1024 + half * 8);
            const unsigned short* pv = (const unsigned short*)&v;
#pragma unroll
            for (int d = 0; d < 8; ++d)
                VsT[(half * 8 + d) * VSTR2 + key] = pv[d];
        }
        __syncthreads();

        // K fragments (A-operand): row kn*16+fm, k=kg*8
        bf16x8 bk[4];
#pragma unroll
        for (int kn = 0; kn < 4; ++kn)
            bk[kn] = *(const bf16x8*)&Ks[(kn * 16 + fm) * KSTR2 + kg * 8];

        // ---- transposed QK + exp2 + packed b64 P-store
#pragma unroll
        for (int kn = 0; kn < 4; ++kn) {
            f32x4 sm[2];
#pragma unroll
            for (int m = 0; m < 2; ++m)
                sm[m] = __builtin_amdgcn_mfma_f32_16x16x32_bf16(
                    bk[kn], aq[m], (f32x4){0.f, 0.f, 0.f, 0.f}, 0, 0, 0);
#pragma unroll
            for (int m = 0; m < 2; ++m) {
                const float p0 = __builtin_amdgcn_exp2f(sm[m][0]);
                const float p1 = __builtin_amdgcn_exp2f(sm[m][1]);
                const float p2 = __builtin_amdgcn_exp2f(sm[m][2]);
                const float p3 = __builtin_amdgcn_exp2f(sm[m][3]);
                lp[m] += (p0 + p1) + (p2 + p3);
                *(uint2*)&Ps[(wq * 32 + m * 16 + fm) * PSTR + kn * 16 + kg * 4] =
                    make_uint2(pkbf(p0, p1), pkbf(p2, p3));
            }
        }

        // ---- PV: O[32q x 16d] += P[32q x 64k] * V[64k x 16d]  (wave-local)
        bf16x8 bv0 = *(const bf16x8*)&VsT[fm * VSTR2 + kg * 8];
        bf16x8 bv1 = *(const bf16x8*)&VsT[fm * VSTR2 + 32 + kg * 8];
#pragma unroll
        for (int m = 0; m < 2; ++m) {
            const int prow = wq * 32 + m * 16 + fm;
            bf16x8 ap0 = *(const bf16x8*)&Ps[prow * PSTR + kg * 8];
            bf16x8 ap1 = *(const bf16x8*)&Ps[prow * PSTR + 32 + kg * 8];
            oacc[m] = __builtin_amdgcn_mfma_f32_16x16x32_bf16(ap0, bv0, oacc[m], 0, 0, 0);
            oacc[m] = __builtin_amdgcn_mfma_f32_16x16x32_bf16(ap1, bv1, oacc[m], 0, 0, 0);
        }
    }

    // l: sum the 4 kg-group partials, transpose via LDS (wave-local)
#pragma unroll
    for (int m = 0; m < 2; ++m) {
        float v = lp[m];
        v += __shfl_xor(v, 16, 64);
        v += __shfl_xor(v, 32, 64);
        if (kg == 0) Lsh[wq * 32 + m * 16 + fm] = v;
    }

    // epilogue: C-layout rows = q (kg*4+r), cols = d (fm)
#pragma unroll
    for (int m = 0; m < 2; ++m) {
        const float4 lr = *(const float4*)&Lsh[wq * 32 + m * 16 + kg * 4];
        const int qrow = q0 + wq * 32 + m * 16 + kg * 4;
        Ob[base + (size_t)(qrow + 0) * 1024 + fm] = f2bf(oacc[m][0] / lr.x);
        Ob[base + (size_t)(qrow + 1) * 1024 + fm] = f2bf(oacc[m][1] / lr.y);
        Ob[base + (size_t)(qrow + 2) * 1024 + fm] = f2bf(oacc[m][2] / lr.z);
        Ob[base + (size_t)(qrow + 3) * 1024 + fm] = f2bf(oacc[m][3] / lr.w);
    }
}

// -------------------------------------------------------------- launch ----
extern "C" void kernel_launch(void* const* d_in, const int* in_sizes, int n_in,
                              void* d_out, int out_size, void* d_ws, size_t ws_size,
                              hipStream_t stream) {
    const float* x  = (const float*)d_in[0];
    const float* Wq = (const float*)d_in[1];
    const float* Wk = (const float*)d_in[2];
    const float* Wv = (const float*)d_in[3];
    const float* Wo = (const float*)d_in[4];
    float* out = (float*)d_out;

    const int M = 2048, N = 1024, Kd = 1024;
    const size_t MEG = 1048576;
    unsigned short* ws = (unsigned short*)d_ws;   // 28 MB high-water
    unsigned short* xb  = ws;
    unsigned short* Wqb = ws + 2 * MEG;
    unsigned short* Wkb = ws + 3 * MEG;
    unsigned short* Wvb = ws + 4 * MEG;
    unsigned short* Wob = ws + 5 * MEG;
    unsigned short* Qb  = ws + 6 * MEG;
    unsigned short* Kb  = ws + 8 * MEG;
    unsigned short* Vb  = ws + 10 * MEG;
    unsigned short* Ob  = ws + 12 * MEG;

    dim3 gc(1024, 6, 1);
    cast_to_bf16<<<gc, 256, 0, stream>>>(x, Wq, Wk, Wv, Wo, xb, Wqb, Wkb, Wvb, Wob);

    dim3 g1(N / 128, M / 64, 3);
    gemm_bt_mfma<<<g1, 256, 0, stream>>>(xb, Wqb, Wkb, Wvb, Qb, Kb, Vb, M, N, Kd, 1);

    dim3 g2(8, 128, 1);
    attn_mfma<<<g2, 256, 0, stream>>>(Qb, Kb, Vb, Ob);

    dim3 g3(N / 128, M / 64, 1);
    gemm_bt_mfma<<<g3, 256, 0, stream>>>(Ob, Wob, Wob, Wob, out, out, out, M, N, Kd, 1 == 0);
}